// Round 6
// baseline (1481.879 us; speedup 1.0000x reference)
//
#include <hip/hip_runtime.h>
#include <hip/hip_bf16.h>
#include <hip/hip_fp16.h>

// tanh-RNN + FC on MI355X.
// conv_w -> gemm_xproj (f16 MFMA, scan-native xp layout) -> rnn_scan6
// (64 blocks = 32 batch-groups x 2 j-halves; 256 thr, 1 wave/SIMD; each wave
// holds 64 W_hh B-frags in 256 AGPRs via "+a" pin + builtin MFMA; pair
// h-exchange via same-XCD hbuf + monotonic flags) -> gemm_logits (in-place).

typedef _Float16 half8 __attribute__((ext_vector_type(8)));
typedef _Float16 half4 __attribute__((ext_vector_type(4)));
typedef float f32x4 __attribute__((ext_vector_type(4)));

// ws layout (bytes)
#define XPW_OFF   0UL            // 64MB x_proj f16 (scan-native layout)
#define WIH_OFF   67108864UL     // 512KB f16 W_ih
#define FCW_OFF   67633152UL     // 256KB f16 fc_w
#define BIAS_OFF  67895296UL     // 2KB f32 bias2
#define WRES_OFF  67897344UL     // 512KB W_hh frags [w(8)][f(64)][lane(64)][8]
#define HBUF_OFF  68421632UL     // 1MB: [2][512][512] f16
#define FLAGS_OFF 69470208UL     // 4KB: 64 flags, 64B apart

// ---------------------------------------------------------------------------
// conv_w: f16 W_ih, fc_w; bias2 = b_ih + b_hh; W_hh -> B-frag layout wres.
// wres[w*32768 + f*512 + l*8 + i] = Whh[(w*64 + (f>>4)*16 + (l&15))*512
//                                       + (f&15)*32 + (l>>4)*8 + i]
// ---------------------------------------------------------------------------
__global__ void conv_w(const float* __restrict__ Wih, const float* __restrict__ Whh,
                       const float* __restrict__ fcw, const float* __restrict__ bih,
                       const float* __restrict__ bhh,
                       _Float16* __restrict__ wih_h, _Float16* __restrict__ fcw_h,
                       float* __restrict__ bias2, _Float16* __restrict__ wres) {
    int idx = blockIdx.x * 256 + threadIdx.x;
    if (idx < 262144) {
        wih_h[idx] = (_Float16)Wih[idx];
        const int i = idx & 7, l = (idx >> 3) & 63, f = (idx >> 9) & 63, w = idx >> 15;
        const int row = w * 64 + ((f >> 4) << 4) + (l & 15);
        const int k = (f & 15) * 32 + (l >> 4) * 8 + i;
        wres[idx] = (_Float16)Whh[(size_t)row * 512 + k];
    }
    if (idx < 131072) fcw_h[idx] = (_Float16)fcw[idx];
    if (idx < 512) bias2[idx] = bih[idx] + bhh[idx];
}

// ---------------------------------------------------------------------------
// K1: x_proj = states @ W_ih^T + bias2, stored scan-native:
//   xps[(bg*128+t)*8192 + ws*1024 + kg*256 + ln*16 + q*4 + n]
//   where batch b = bg*16 + kg*4 + q, col = ws*64 + n*16 + ln.
// ---------------------------------------------------------------------------
__global__ __launch_bounds__(256) void gemm_xproj(const float* __restrict__ A,
                                                  const _Float16* __restrict__ Bw,
                                                  const float* __restrict__ bias2,
                                                  _Float16* __restrict__ out) {
    __shared__ _Float16 As[128 * 32];
    __shared__ _Float16 Bs[128 * 32];
    const int tid = threadIdx.x;
    const int s_ = blockIdx.x;
    const int z = s_ & 7, kk = s_ >> 3;
    const int blow = kk & 3;
    const int gq = z * 64 + (kk >> 2);
    const int gp = gq >> 2, nq = gq & 3;
    const int b = gp * 4 + blow;
    const int m0 = b << 7;
    const int n0 = nq << 7;
    const int lane = tid & 63, w = tid >> 6;
    const int wr = (w >> 1) * 64, wc = (w & 1) * 64;
    const int ln = lane & 15, kg = lane >> 4;

    f32x4 acc[4][4];
#pragma unroll
    for (int m = 0; m < 4; m++)
#pragma unroll
        for (int n = 0; n < 4; n++) acc[m][n] = (f32x4)0.0f;

    const int sr = tid >> 1;
    const int sc = (tid & 1) * 16;

    for (int k0 = 0; k0 < 512; k0 += 32) {
        {
            const float* ga = A + (size_t)(m0 + sr) * 512 + k0 + sc;
            float4 f0 = *(const float4*)(ga + 0);
            float4 f1 = *(const float4*)(ga + 4);
            float4 f2 = *(const float4*)(ga + 8);
            float4 f3 = *(const float4*)(ga + 12);
            half8 h0, h1;
            h0[0] = (_Float16)f0.x; h0[1] = (_Float16)f0.y; h0[2] = (_Float16)f0.z; h0[3] = (_Float16)f0.w;
            h0[4] = (_Float16)f1.x; h0[5] = (_Float16)f1.y; h0[6] = (_Float16)f1.z; h0[7] = (_Float16)f1.w;
            h1[0] = (_Float16)f2.x; h1[1] = (_Float16)f2.y; h1[2] = (_Float16)f2.z; h1[3] = (_Float16)f2.w;
            h1[4] = (_Float16)f3.x; h1[5] = (_Float16)f3.y; h1[6] = (_Float16)f3.z; h1[7] = (_Float16)f3.w;
            *(half8*)&As[sr * 32 + sc] = h0;
            *(half8*)&As[sr * 32 + sc + 8] = h1;
        }
        {
            const _Float16* gb = Bw + (size_t)(n0 + sr) * 512 + k0 + sc;
            *(half8*)&Bs[sr * 32 + sc] = *(const half8*)(gb);
            *(half8*)&Bs[sr * 32 + sc + 8] = *(const half8*)(gb + 8);
        }
        __syncthreads();
        half8 af[4], bf[4];
#pragma unroll
        for (int m = 0; m < 4; m++) af[m] = *(const half8*)&As[(wr + m * 16 + ln) * 32 + kg * 8];
#pragma unroll
        for (int n = 0; n < 4; n++) bf[n] = *(const half8*)&Bs[(wc + n * 16 + ln) * 32 + kg * 8];
#pragma unroll
        for (int m = 0; m < 4; m++)
#pragma unroll
            for (int n = 0; n < 4; n++)
                acc[m][n] = __builtin_amdgcn_mfma_f32_16x16x32_f16(af[m], bf[n], acc[m][n], 0, 0, 0);
        __syncthreads();
    }
    const int bg2 = b >> 4, kgs = (b >> 2) & 3, qs = b & 3;
    const int col0 = n0 + wc;
    const int ws_ = col0 >> 6;
    float bv[4];
#pragma unroll
    for (int n = 0; n < 4; n++) bv[n] = bias2[col0 + n * 16 + ln];
    const size_t tb = (size_t)(bg2 * 128) * 8192 + (size_t)ws_ * 1024
                    + (size_t)kgs * 256 + (size_t)ln * 16 + qs * 4;
#pragma unroll
    for (int m = 0; m < 4; m++)
#pragma unroll
        for (int q = 0; q < 4; q++) {
            half4 v;
#pragma unroll
            for (int n = 0; n < 4; n++) v[n] = (_Float16)(acc[m][n][q] + bv[n]);
            const int t = wr + m * 16 + kg * 4 + q;
            *(half4*)&out[tb + (size_t)t * 8192] = v;
        }
}

// ---------------------------------------------------------------------------
// Scan v6: 64 blocks = 32 batch-groups x 2 j-halves; 256 thr (4 waves,
// 1/SIMD, 512-reg budget). Wave w owns 64 j-cols: 64 B-frags in 256 AGPRs
// ("+a" pin + builtin MFMA). h in k8-major LDS. Pair exchange: own h-half
// through hbuf (agent atomics) + monotonic flags; partner = bid^32 (same XCD
// under round-robin; correct regardless).
// ---------------------------------------------------------------------------
__global__ __launch_bounds__(256, 1) void rnn_scan6(
    const _Float16* __restrict__ xps,    // scan-native x_proj
    const _Float16* __restrict__ wres,   // B-frag W_hh
    const int* __restrict__ term,        // [512][128] int32
    const float* __restrict__ h0,        // [512][512] f32
    _Float16* __restrict__ hbuf,         // [2][512][512] f16
    int* __restrict__ flags,             // 64 flags, stride 16 ints
    float* dout) {
    __shared__ __align__(16) _Float16 hb[8192];   // [kblock(64)][row(16)*8 + k&7]
    __shared__ unsigned int term_lds[16][4];
    const int tid = threadIdx.x;
    const int bid = blockIdx.x;
    const int half = bid >> 5;            // j-half
    const int bg = bid & 31;              // batch-group
    const int R0 = bg * 16;
    const int jb0 = half * 256;
    const int pjb0 = jb0 ^ 256;
    const int lane = tid & 63, w = tid >> 6;   // 4 waves
    const int ln = lane & 15, kg = lane >> 4;
    const int ws_ = half * 4 + w;         // global 64-col group 0..7
    const int sOwn = half * 8;            // own k-slices (global s)
    const int sPar = 8 - sOwn;            // partner k-slices
    _Float16* rnn = (_Float16*)dout;
    int* myflag = flags + bid * 16;
    int* pflag  = flags + (bid ^ 32) * 16;

    // ---- 64 B-frags -> 256 AGPRs ----
    half8 wf[64];
    {
        const _Float16* wp = wres + ((size_t)ws_ * 4096 + lane) * 8;
#pragma unroll
        for (int f = 0; f < 64; f++) wf[f] = *(const half8*)(wp + (size_t)f * 512);
    }
#pragma unroll
    for (int f = 0; f < 64; f++) asm volatile("" : "+a"(wf[f]));

    // ---- h0 -> hb (f32 -> f16, k8-major) ----
    {
        const int r = tid >> 4, c0 = (tid & 15) * 32;
        const float* gh = h0 + (size_t)(R0 + r) * 512 + c0;
#pragma unroll
        for (int u = 0; u < 4; u++) {
            half8 v;
#pragma unroll
            for (int i = 0; i < 8; i++) v[i] = (_Float16)gh[u * 8 + i];
            *(half8*)&hb[((c0 >> 3) + u) * 128 + r * 8] = v;
        }
    }
    // ---- termination bitmasks ----
    if (tid < 64) {
        const int r = tid >> 2, word = tid & 3;
        unsigned int m = 0;
        for (int b2 = 0; b2 < 32; b2++)
            m |= (term[(R0 + r) * 128 + word * 32 + b2] ? 1u : 0u) << b2;
        term_lds[r][word] = m;
    }
    __syncthreads();

    const _Float16* xpt = xps + (size_t)(bg * 128) * 8192 + ws_ * 1024 + kg * 256 + ln * 16;
    const int rr = tid >> 4, kq = tid & 15;   // exchange-copy mapping
    unsigned int tmask[4];
    typedef unsigned long long u64;

#pragma unroll 1
    for (int t = 0; t < 128; ++t) {
        if ((t & 31) == 0) {
#pragma unroll
            for (int q = 0; q < 4; q++) tmask[q] = term_lds[kg * 4 + q][t >> 5];
        }
        // xp(t) — issued early, consumed in phase 2
        const _Float16* xn = xpt + (size_t)t * 8192;
        const half8 xa0 = *(const half8*)(xn);
        const half8 xa1 = *(const half8*)(xn + 8);

        f32x4 acc[4];
#pragma unroll
        for (int n = 0; n < 4; n++) acc[n] = (f32x4)0.0f;

        // ---- own k-slices (no partner dependency) ----
#pragma unroll
        for (int so = 0; so < 8; so++) {
            const int s = sOwn + so;
            const half8 a = *(const half8*)&hb[(s * 4 + kg) * 128 + ln * 8];
            acc[0] = __builtin_amdgcn_mfma_f32_16x16x32_f16(a, wf[s],      acc[0], 0, 0, 0);
            acc[1] = __builtin_amdgcn_mfma_f32_16x16x32_f16(a, wf[16 + s], acc[1], 0, 0, 0);
            acc[2] = __builtin_amdgcn_mfma_f32_16x16x32_f16(a, wf[32 + s], acc[2], 0, 0, 0);
            acc[3] = __builtin_amdgcn_mfma_f32_16x16x32_f16(a, wf[48 + s], acc[3], 0, 0, 0);
        }

        // ---- handshake: import partner half of h(t) ----
        if (t > 0 && tid == 0) {
            while (__hip_atomic_load(pflag, __ATOMIC_ACQUIRE, __HIP_MEMORY_SCOPE_AGENT) < t) {}
        }
        __syncthreads();
        if (t > 0) {
            const u64* src = (const u64*)(hbuf + (size_t)(t & 1) * 262144
                                          + (size_t)(R0 + rr) * 512 + pjb0 + kq * 16);
            union { half8 v; u64 u[2]; } d0, d1;
            d0.u[0] = __hip_atomic_load(src + 0, __ATOMIC_RELAXED, __HIP_MEMORY_SCOPE_AGENT);
            d0.u[1] = __hip_atomic_load(src + 1, __ATOMIC_RELAXED, __HIP_MEMORY_SCOPE_AGENT);
            d1.u[0] = __hip_atomic_load(src + 2, __ATOMIC_RELAXED, __HIP_MEMORY_SCOPE_AGENT);
            d1.u[1] = __hip_atomic_load(src + 3, __ATOMIC_RELAXED, __HIP_MEMORY_SCOPE_AGENT);
            *(half8*)&hb[((pjb0 >> 3) + kq * 2) * 128 + rr * 8] = d0.v;
            *(half8*)&hb[((pjb0 >> 3) + kq * 2 + 1) * 128 + rr * 8] = d1.v;
        }
        __syncthreads();

        // ---- partner k-slices ----
#pragma unroll
        for (int so = 0; so < 8; so++) {
            const int s = sPar + so;
            const half8 a = *(const half8*)&hb[(s * 4 + kg) * 128 + ln * 8];
            acc[0] = __builtin_amdgcn_mfma_f32_16x16x32_f16(a, wf[s],      acc[0], 0, 0, 0);
            acc[1] = __builtin_amdgcn_mfma_f32_16x16x32_f16(a, wf[16 + s], acc[1], 0, 0, 0);
            acc[2] = __builtin_amdgcn_mfma_f32_16x16x32_f16(a, wf[32 + s], acc[2], 0, 0, 0);
            acc[3] = __builtin_amdgcn_mfma_f32_16x16x32_f16(a, wf[48 + s], acc[3], 0, 0, 0);
        }
        __syncthreads();   // all hb reads of h(t) done

        // ---- phase 2: tanh; masked h(t+1) -> hb ----
        _Float16 hh[16];
#pragma unroll
        for (int n = 0; n < 4; n++)
#pragma unroll
            for (int q = 0; q < 4; q++) {
                const int u = q * 4 + n;
                const float xval = (float)(u < 8 ? xa0[u] : xa1[u - 8]);
                const float pre = acc[n][q] + xval;
                const float e = __expf(2.0f * pre);
                const float hn = 1.0f - 2.0f / (e + 1.0f);
                hh[n * 4 + q] = (_Float16)hn;
                const int col = jb0 + w * 64 + n * 16 + ln;
                hb[(col >> 3) * 128 + (kg * 4 + q) * 8 + (col & 7)] =
                    ((tmask[q] >> (t & 31)) & 1) ? (_Float16)0.0f : hh[n * 4 + q];
            }
        __syncthreads();   // hb own-k of h(t+1) visible

        // ---- export own half of h(t+1), release flag, then rnn stores ----
        if (t < 127) {
            union { half8 v; u64 u[2]; } e0, e1;
            e0.v = *(const half8*)&hb[((jb0 >> 3) + kq * 2) * 128 + rr * 8];
            e1.v = *(const half8*)&hb[((jb0 >> 3) + kq * 2 + 1) * 128 + rr * 8];
            u64* dst = (u64*)(hbuf + (size_t)((t + 1) & 1) * 262144
                              + (size_t)(R0 + rr) * 512 + jb0 + kq * 16);
            __hip_atomic_store(dst + 0, e0.u[0], __ATOMIC_RELAXED, __HIP_MEMORY_SCOPE_AGENT);
            __hip_atomic_store(dst + 1, e0.u[1], __ATOMIC_RELAXED, __HIP_MEMORY_SCOPE_AGENT);
            __hip_atomic_store(dst + 2, e1.u[0], __ATOMIC_RELAXED, __HIP_MEMORY_SCOPE_AGENT);
            __hip_atomic_store(dst + 3, e1.u[1], __ATOMIC_RELAXED, __HIP_MEMORY_SCOPE_AGENT);
        }
        __syncthreads();   // implicit vmcnt(0): exports complete device-wide
        if (t < 127 && tid == 0)
            __hip_atomic_store(myflag, t + 1, __ATOMIC_RELEASE, __HIP_MEMORY_SCOPE_AGENT);

        // unmasked rnn_out (off the partner's critical path)
#pragma unroll
        for (int n = 0; n < 4; n++)
#pragma unroll
            for (int q = 0; q < 4; q++)
                rnn[(size_t)((R0 + kg * 4 + q) * 128 + t) * 512 + jb0 + w * 64 + n * 16 + ln] = hh[n * 4 + q];
    }

    // ---- h_final (masked h(128), own half) -> f32 at d_out + 65536*256 ----
    {
        half8 v0 = *(const half8*)&hb[((jb0 >> 3) + kq * 2) * 128 + rr * 8];
        half8 v1 = *(const half8*)&hb[((jb0 >> 3) + kq * 2 + 1) * 128 + rr * 8];
        float* gf = dout + (size_t)65536 * 256 + (size_t)(R0 + rr) * 512 + jb0 + kq * 16;
#pragma unroll
        for (int i = 0; i < 8; i++) { gf[i] = (float)v0[i]; gf[8 + i] = (float)v1[i]; }
    }
}

// ---------------------------------------------------------------------------
// K3: logits[65536,256] (f32) = rnn_out(f16, in d_out) @ fc_w^T + fc_b
// ---------------------------------------------------------------------------
__global__ __launch_bounds__(512) void gemm_logits(const _Float16* Arnn,
                                                   const _Float16* __restrict__ Bw,
                                                   const float* __restrict__ biasv,
                                                   float* out) {
    __shared__ _Float16 As[128 * 32];
    __shared__ _Float16 Bs[256 * 32];
    const int tid = threadIdx.x;
    const int m0 = blockIdx.x * 128;
    const int lane = tid & 63, w = tid >> 6;
    const int wr = (w >> 2) * 64, wc = (w & 3) * 64;
    const int ln = lane & 15, kg = lane >> 4;

    f32x4 acc[4][4];
#pragma unroll
    for (int m = 0; m < 4; m++)
#pragma unroll
        for (int n = 0; n < 4; n++) acc[m][n] = (f32x4)0.0f;

    const int ar = tid >> 2, ac = (tid & 3) * 8;
    const int br = tid >> 1, bc = (tid & 1) * 16;

    for (int k0 = 0; k0 < 512; k0 += 32) {
        *(half8*)&As[ar * 32 + ac] = *(const half8*)(Arnn + (size_t)(m0 + ar) * 512 + k0 + ac);
        {
            const _Float16* gb = Bw + (size_t)br * 512 + k0 + bc;
            *(half8*)&Bs[br * 32 + bc] = *(const half8*)(gb);
            *(half8*)&Bs[br * 32 + bc + 8] = *(const half8*)(gb + 8);
        }
        __syncthreads();
        half8 af[4], bf[4];
#pragma unroll
        for (int m = 0; m < 4; m++) af[m] = *(const half8*)&As[(wr + m * 16 + ln) * 32 + kg * 8];
#pragma unroll
        for (int n = 0; n < 4; n++) bf[n] = *(const half8*)&Bs[(wc + n * 16 + ln) * 32 + kg * 8];
#pragma unroll
        for (int m = 0; m < 4; m++)
#pragma unroll
            for (int n = 0; n < 4; n++)
                acc[m][n] = __builtin_amdgcn_mfma_f32_16x16x32_f16(af[m], bf[n], acc[m][n], 0, 0, 0);
        __syncthreads();
    }
#pragma unroll
    for (int m = 0; m < 4; m++)
#pragma unroll
        for (int n = 0; n < 4; n++) {
            const int col = wc + n * 16 + ln;
            const float bv = biasv[col];
#pragma unroll
            for (int q = 0; q < 4; q++) {
                const int row = m0 + wr + m * 16 + kg * 4 + q;
                out[(size_t)row * 256 + col] = acc[m][n][q] + bv;
            }
        }
}

// ---------------------------------------------------------------------------
extern "C" void kernel_launch(void* const* d_in, const int* in_sizes, int n_in,
                              void* d_out, int out_size, void* d_ws, size_t ws_size,
                              hipStream_t stream) {
    const float* states = (const float*)d_in[0];
    const int*   term   = (const int*)d_in[1];
    const float* h0     = (const float*)d_in[2];
    const float* Wih    = (const float*)d_in[3];
    const float* Whh    = (const float*)d_in[4];
    const float* bih    = (const float*)d_in[5];
    const float* bhh    = (const float*)d_in[6];
    const float* fcw    = (const float*)d_in[7];
    const float* fcb    = (const float*)d_in[8];

    char* ws = (char*)d_ws;
    _Float16* xpw   = (_Float16*)(ws + XPW_OFF);
    _Float16* wih_h = (_Float16*)(ws + WIH_OFF);
    _Float16* fcw_h = (_Float16*)(ws + FCW_OFF);
    float*    bias2 = (float*)(ws + BIAS_OFF);
    _Float16* wres  = (_Float16*)(ws + WRES_OFF);
    _Float16* hbuf  = (_Float16*)(ws + HBUF_OFF);
    int*      flags = (int*)(ws + FLAGS_OFF);

    conv_w<<<1024, 256, 0, stream>>>(Wih, Whh, fcw, bih, bhh, wih_h, fcw_h, bias2, wres);
    gemm_xproj<<<2048, 256, 0, stream>>>(states, wih_h, bias2, xpw);
    hipMemsetAsync(flags, 0, 4096, stream);
    rnn_scan6<<<64, 256, 0, stream>>>(xpw, wres, term, h0, hbuf, flags, (float*)d_out);
    gemm_logits<<<512, 512, 0, stream>>>((const _Float16*)d_out, fcw_h, fcb, (float*)d_out);
}

// Round 7
// 951.778 us; speedup vs baseline: 1.5570x; 1.5570x over previous
//
#include <hip/hip_runtime.h>
#include <hip/hip_bf16.h>
#include <hip/hip_fp16.h>

// tanh-RNN + FC on MI355X.
// conv_w -> gemm_xproj (f16 MFMA, scan-native xp layout) -> rnn_scan7
// (32 blocks x 256 thr, 1 wave/SIMD; W_hh split: 256KB in AGPRs (4 waves x
// 256 "+a"-pinned) + 128KB LDS-resident + 128KB/step L2-streamed; NO
// inter-block communication) -> gemm_logits (in-place over d_out).

typedef _Float16 half8 __attribute__((ext_vector_type(8)));
typedef _Float16 half4 __attribute__((ext_vector_type(4)));
typedef float f32x4 __attribute__((ext_vector_type(4)));

// ws layout (bytes)
#define XPW_OFF   0UL            // 64MB x_proj f16 (scan-native layout)
#define WIH_OFF   67108864UL     // 512KB f16 W_ih
#define FCW_OFF   67633152UL     // 256KB f16 fc_w
#define BIAS_OFF  67895296UL     // 2KB f32 bias2
#define WRES_OFF  67897344UL     // 512KB W_hh frags [grp(8)][s(16)][nt(4)][lane(64)][8]

// ---------------------------------------------------------------------------
// conv_w: f16 W_ih, fc_w; bias2 = b_ih + b_hh; W_hh -> frag layout wres:
// wres[grp*32768 + s*2048 + nt*512 + l*8 + i]
//   = Whh[(grp*64 + nt*16 + (l&15))*512 + s*32 + (l>>4)*8 + i]
// ---------------------------------------------------------------------------
__global__ void conv_w(const float* __restrict__ Wih, const float* __restrict__ Whh,
                       const float* __restrict__ fcw, const float* __restrict__ bih,
                       const float* __restrict__ bhh,
                       _Float16* __restrict__ wih_h, _Float16* __restrict__ fcw_h,
                       float* __restrict__ bias2, _Float16* __restrict__ wres) {
    int idx = blockIdx.x * 256 + threadIdx.x;
    if (idx < 262144) {
        wih_h[idx] = (_Float16)Wih[idx];
        const int i = idx & 7, l = (idx >> 3) & 63;
        const int nt = (idx >> 9) & 3, s = (idx >> 11) & 15, grp = idx >> 15;
        const int row = grp * 64 + nt * 16 + (l & 15);
        const int k = s * 32 + (l >> 4) * 8 + i;
        wres[idx] = (_Float16)Whh[(size_t)row * 512 + k];
    }
    if (idx < 131072) fcw_h[idx] = (_Float16)fcw[idx];
    if (idx < 512) bias2[idx] = bih[idx] + bhh[idx];
}

// ---------------------------------------------------------------------------
// K1: x_proj = states @ W_ih^T + bias2, stored scan-native:
//   dst = (bg*128+t)*8192 + (w_s*64 + kg_s*16 + ln_s)*32 + q_s*8 + nt_b + n
//   where b = bg*16 + kg_s*4 + q_s, col c: slab=c>>6, w_s=slab&3,
//   nt_b=(slab&4), n=(c>>4)&3, ln_s=c&15.
// ---------------------------------------------------------------------------
__global__ __launch_bounds__(256) void gemm_xproj(const float* __restrict__ A,
                                                  const _Float16* __restrict__ Bw,
                                                  const float* __restrict__ bias2,
                                                  _Float16* __restrict__ out) {
    __shared__ _Float16 As[128 * 32];
    __shared__ _Float16 Bs[128 * 32];
    const int tid = threadIdx.x;
    const int s_ = blockIdx.x;
    const int z = s_ & 7, kk = s_ >> 3;
    const int blow = kk & 3;
    const int gq = z * 64 + (kk >> 2);
    const int gp = gq >> 2, nq = gq & 3;
    const int b = gp * 4 + blow;
    const int m0 = b << 7;
    const int n0 = nq << 7;
    const int lane = tid & 63, w = tid >> 6;
    const int wr = (w >> 1) * 64, wc = (w & 1) * 64;
    const int ln = lane & 15, kg = lane >> 4;

    f32x4 acc[4][4];
#pragma unroll
    for (int m = 0; m < 4; m++)
#pragma unroll
        for (int n = 0; n < 4; n++) acc[m][n] = (f32x4)0.0f;

    const int sr = tid >> 1;
    const int sc = (tid & 1) * 16;

    for (int k0 = 0; k0 < 512; k0 += 32) {
        {
            const float* ga = A + (size_t)(m0 + sr) * 512 + k0 + sc;
            float4 f0 = *(const float4*)(ga + 0);
            float4 f1 = *(const float4*)(ga + 4);
            float4 f2 = *(const float4*)(ga + 8);
            float4 f3 = *(const float4*)(ga + 12);
            half8 h0, h1;
            h0[0] = (_Float16)f0.x; h0[1] = (_Float16)f0.y; h0[2] = (_Float16)f0.z; h0[3] = (_Float16)f0.w;
            h0[4] = (_Float16)f1.x; h0[5] = (_Float16)f1.y; h0[6] = (_Float16)f1.z; h0[7] = (_Float16)f1.w;
            h1[0] = (_Float16)f2.x; h1[1] = (_Float16)f2.y; h1[2] = (_Float16)f2.z; h1[3] = (_Float16)f2.w;
            h1[4] = (_Float16)f3.x; h1[5] = (_Float16)f3.y; h1[6] = (_Float16)f3.z; h1[7] = (_Float16)f3.w;
            *(half8*)&As[sr * 32 + sc] = h0;
            *(half8*)&As[sr * 32 + sc + 8] = h1;
        }
        {
            const _Float16* gb = Bw + (size_t)(n0 + sr) * 512 + k0 + sc;
            *(half8*)&Bs[sr * 32 + sc] = *(const half8*)(gb);
            *(half8*)&Bs[sr * 32 + sc + 8] = *(const half8*)(gb + 8);
        }
        __syncthreads();
        half8 af[4], bf[4];
#pragma unroll
        for (int m = 0; m < 4; m++) af[m] = *(const half8*)&As[(wr + m * 16 + ln) * 32 + kg * 8];
#pragma unroll
        for (int n = 0; n < 4; n++) bf[n] = *(const half8*)&Bs[(wc + n * 16 + ln) * 32 + kg * 8];
#pragma unroll
        for (int m = 0; m < 4; m++)
#pragma unroll
            for (int n = 0; n < 4; n++)
                acc[m][n] = __builtin_amdgcn_mfma_f32_16x16x32_f16(af[m], bf[n], acc[m][n], 0, 0, 0);
        __syncthreads();
    }
    const int bg2 = b >> 4, kgs = (b >> 2) & 3, qs = b & 3;
    const int col0 = n0 + wc;                 // multiple of 64
    const int slab = col0 >> 6;
    const int w_s = slab & 3;
    const int nt_b = slab & 4;
    float bv[4];
#pragma unroll
    for (int n = 0; n < 4; n++) bv[n] = bias2[col0 + n * 16 + ln];
    const size_t tb = (size_t)(bg2 * 128) * 8192 + (size_t)(w_s * 64 + kgs * 16 + ln) * 32
                    + qs * 8 + nt_b;
#pragma unroll
    for (int m = 0; m < 4; m++)
#pragma unroll
        for (int q = 0; q < 4; q++) {
            half4 v;
#pragma unroll
            for (int n = 0; n < 4; n++) v[n] = (_Float16)(acc[m][n][q] + bv[n]);
            const int t = wr + m * 16 + kg * 4 + q;
            *(half4*)&out[tb + (size_t)t * 8192] = v;
        }
}

// ---------------------------------------------------------------------------
// Scan v7: 32 blocks x 256 thr (4 waves, 1/SIMD, 512-reg budget). Wave w owns
// j-slabs {w, 4+w} (128 cols, 8 n-tiles): slab w in 256 AGPRs; slab 4+w from
// LDS (waves 0,1) or L2-streamed with depth-16 rolling prefetch (waves 2,3).
// h in k8-major LDS. Zero inter-block communication.
// ---------------------------------------------------------------------------
__global__ __launch_bounds__(256, 1) void rnn_scan7(
    const _Float16* __restrict__ xps,    // scan-native x_proj
    const _Float16* __restrict__ wres,   // frag-layout W_hh
    const int* __restrict__ term,        // [512][128] int32
    const float* __restrict__ h0,        // [512][512] f32
    float* dout) {
    __shared__ __align__(16) _Float16 hb[8192];      // h, k8-major: [(k>>3)][row*8+(k&7)]
    __shared__ __align__(16) _Float16 wlds[65536];   // W slabs 4,5 (128KB)
    __shared__ unsigned int term_lds[16][4];
    const int tid = threadIdx.x;
    const int bg = blockIdx.x;
    const int R0 = bg * 16;
    const int lane = tid & 63, w = tid >> 6;
    const int ln = lane & 15, kg = lane >> 4;
    _Float16* rnn = (_Float16*)dout;

    // ---- AGPR slab w: 64 frags (f' = s*4+nt) = 256 AGPRs ----
    half8 wf[64];
    {
        const _Float16* wp = wres + (size_t)w * 32768 + lane * 8;
#pragma unroll
        for (int f = 0; f < 64; f++) wf[f] = *(const half8*)(wp + (size_t)f * 512);
    }
#pragma unroll
    for (int f = 0; f < 64; f++) asm volatile("" : "+a"(wf[f]));

    // ---- stage slabs 4,5 into LDS (131072B, linear copy) ----
    {
        const _Float16* src = wres + 131072;
        for (int u = 0; u < 32; u++) {
            const int o = (u * 256 + tid) * 8;
            *(half8*)&wlds[o] = *(const half8*)(src + o);
        }
    }
    // ---- h0 -> hb (f32 -> f16, k8-major) ----
    {
        const int r = tid >> 4, c0 = (tid & 15) * 32;
        const float* gh = h0 + (size_t)(R0 + r) * 512 + c0;
#pragma unroll
        for (int u = 0; u < 4; u++) {
            half8 v;
#pragma unroll
            for (int i = 0; i < 8; i++) v[i] = (_Float16)gh[u * 8 + i];
            *(half8*)&hb[((c0 >> 3) + u) * 128 + r * 8] = v;
        }
    }
    // ---- termination bitmasks ----
    if (tid < 64) {
        const int r = tid >> 2, word = tid & 3;
        unsigned int m = 0;
        for (int b2 = 0; b2 < 32; b2++)
            m |= (term[(R0 + r) * 128 + word * 32 + b2] ? 1u : 0u) << b2;
        term_lds[r][word] = m;
    }
    __syncthreads();

    // ---- streamed slab prefetch (waves 2,3; slab 4+w = grp 6,7) ----
    const _Float16* wsb = wres + (size_t)(4 + w) * 32768;   // only used for w>=2
    half8 wst[16];
    if (w >= 2) {
#pragma unroll
        for (int p = 0; p < 16; p++) wst[p] = *(const half8*)(wsb + p * 512 + lane * 8);
    }

    const _Float16* xpt = xps + (size_t)(bg * 128) * 8192 + tid * 32;
    const _Float16* bl = &wlds[(size_t)w * 32768];          // only used for w<2
    unsigned int tmask[4];

#pragma unroll 1
    for (int t = 0; t < 128; ++t) {
        if ((t & 31) == 0) {
#pragma unroll
            for (int q = 0; q < 4; q++) tmask[q] = term_lds[kg * 4 + q][t >> 5];
        }
        // xp(t): 64B contiguous per thread, xv[q][nt]
        half8 xv[4];
#pragma unroll
        for (int q = 0; q < 4; q++) xv[q] = *(const half8*)(xpt + (size_t)t * 8192 + q * 8);

        f32x4 acc[8];
#pragma unroll
        for (int n = 0; n < 8; n++) acc[n] = (f32x4)0.0f;

        if (w < 2) {
#pragma unroll
            for (int s = 0; s < 16; s++) {
                const half8 a = *(const half8*)&hb[(s * 4 + kg) * 128 + ln * 8];
                acc[0] = __builtin_amdgcn_mfma_f32_16x16x32_f16(a, wf[s * 4 + 0], acc[0], 0, 0, 0);
                acc[1] = __builtin_amdgcn_mfma_f32_16x16x32_f16(a, wf[s * 4 + 1], acc[1], 0, 0, 0);
                acc[2] = __builtin_amdgcn_mfma_f32_16x16x32_f16(a, wf[s * 4 + 2], acc[2], 0, 0, 0);
                acc[3] = __builtin_amdgcn_mfma_f32_16x16x32_f16(a, wf[s * 4 + 3], acc[3], 0, 0, 0);
                const half8 b0 = *(const half8*)(bl + (s * 4 + 0) * 512 + lane * 8);
                const half8 b1 = *(const half8*)(bl + (s * 4 + 1) * 512 + lane * 8);
                const half8 b2 = *(const half8*)(bl + (s * 4 + 2) * 512 + lane * 8);
                const half8 b3 = *(const half8*)(bl + (s * 4 + 3) * 512 + lane * 8);
                acc[4] = __builtin_amdgcn_mfma_f32_16x16x32_f16(a, b0, acc[4], 0, 0, 0);
                acc[5] = __builtin_amdgcn_mfma_f32_16x16x32_f16(a, b1, acc[5], 0, 0, 0);
                acc[6] = __builtin_amdgcn_mfma_f32_16x16x32_f16(a, b2, acc[6], 0, 0, 0);
                acc[7] = __builtin_amdgcn_mfma_f32_16x16x32_f16(a, b3, acc[7], 0, 0, 0);
            }
        } else {
#pragma unroll
            for (int s = 0; s < 16; s++) {
                const half8 a = *(const half8*)&hb[(s * 4 + kg) * 128 + ln * 8];
                acc[0] = __builtin_amdgcn_mfma_f32_16x16x32_f16(a, wf[s * 4 + 0], acc[0], 0, 0, 0);
                acc[1] = __builtin_amdgcn_mfma_f32_16x16x32_f16(a, wf[s * 4 + 1], acc[1], 0, 0, 0);
                acc[2] = __builtin_amdgcn_mfma_f32_16x16x32_f16(a, wf[s * 4 + 2], acc[2], 0, 0, 0);
                acc[3] = __builtin_amdgcn_mfma_f32_16x16x32_f16(a, wf[s * 4 + 3], acc[3], 0, 0, 0);
                acc[4] = __builtin_amdgcn_mfma_f32_16x16x32_f16(a, wst[(s * 4 + 0) & 15], acc[4], 0, 0, 0);
                acc[5] = __builtin_amdgcn_mfma_f32_16x16x32_f16(a, wst[(s * 4 + 1) & 15], acc[5], 0, 0, 0);
                acc[6] = __builtin_amdgcn_mfma_f32_16x16x32_f16(a, wst[(s * 4 + 2) & 15], acc[6], 0, 0, 0);
                acc[7] = __builtin_amdgcn_mfma_f32_16x16x32_f16(a, wst[(s * 4 + 3) & 15], acc[7], 0, 0, 0);
                // refill consumed slots with frags 4 s-slices ahead (wraps mod 64: W constant over t)
                wst[(s * 4 + 0) & 15] = *(const half8*)(wsb + (((s + 4) * 4 + 0) & 63) * 512 + lane * 8);
                wst[(s * 4 + 1) & 15] = *(const half8*)(wsb + (((s + 4) * 4 + 1) & 63) * 512 + lane * 8);
                wst[(s * 4 + 2) & 15] = *(const half8*)(wsb + (((s + 4) * 4 + 2) & 63) * 512 + lane * 8);
                wst[(s * 4 + 3) & 15] = *(const half8*)(wsb + (((s + 4) * 4 + 3) & 63) * 512 + lane * 8);
            }
        }
        __syncthreads();   // all hb reads of h(t) done

        // ---- tanh; masked h(t+1) -> hb ----
        _Float16 hh[32];
#pragma unroll
        for (int q = 0; q < 4; q++)
#pragma unroll
            for (int n = 0; n < 8; n++) {
                const float pre = acc[n][q] + (float)xv[q][n];
                const float e = __expf(2.0f * pre);
                const float hn = 1.0f - 2.0f / (e + 1.0f);
                hh[q * 8 + n] = (_Float16)hn;
                const int c = (n < 4) ? (w * 64 + n * 16 + ln)
                                      : (256 + w * 64 + (n - 4) * 16 + ln);
                hb[(c >> 3) * 128 + (kg * 4 + q) * 8 + (c & 7)] =
                    ((tmask[q] >> (t & 31)) & 1) ? (_Float16)0.0f : hh[q * 8 + n];
            }
        __syncthreads();   // h(t+1) visible

        // ---- rnn_out stores (after barrier: drain overlaps next MFMA phase) ----
#pragma unroll
        for (int q = 0; q < 4; q++)
#pragma unroll
            for (int n = 0; n < 8; n++) {
                const int c = (n < 4) ? (w * 64 + n * 16 + ln)
                                      : (256 + w * 64 + (n - 4) * 16 + ln);
                rnn[(size_t)((R0 + kg * 4 + q) * 128 + t) * 512 + c] = hh[q * 8 + n];
            }
    }

    // ---- h_final (masked h(128)) -> f32 at d_out + 65536*256 ----
    {
        const int r = tid >> 4, c0 = (tid & 15) * 32;
        float* gf = dout + (size_t)65536 * 256 + (size_t)(R0 + r) * 512 + c0;
#pragma unroll
        for (int u = 0; u < 4; u++) {
            half8 v = *(const half8*)&hb[((c0 >> 3) + u) * 128 + r * 8];
#pragma unroll
            for (int i = 0; i < 8; i++) gf[u * 8 + i] = (float)v[i];
        }
    }
}

// ---------------------------------------------------------------------------
// K3: logits[65536,256] (f32) = rnn_out(f16, in d_out) @ fc_w^T + fc_b
// ---------------------------------------------------------------------------
__global__ __launch_bounds__(512) void gemm_logits(const _Float16* Arnn,
                                                   const _Float16* __restrict__ Bw,
                                                   const float* __restrict__ biasv,
                                                   float* out) {
    __shared__ _Float16 As[128 * 32];
    __shared__ _Float16 Bs[256 * 32];
    const int tid = threadIdx.x;
    const int m0 = blockIdx.x * 128;
    const int lane = tid & 63, w = tid >> 6;
    const int wr = (w >> 2) * 64, wc = (w & 3) * 64;
    const int ln = lane & 15, kg = lane >> 4;

    f32x4 acc[4][4];
#pragma unroll
    for (int m = 0; m < 4; m++)
#pragma unroll
        for (int n = 0; n < 4; n++) acc[m][n] = (f32x4)0.0f;

    const int ar = tid >> 2, ac = (tid & 3) * 8;
    const int br = tid >> 1, bc = (tid & 1) * 16;

    for (int k0 = 0; k0 < 512; k0 += 32) {
        *(half8*)&As[ar * 32 + ac] = *(const half8*)(Arnn + (size_t)(m0 + ar) * 512 + k0 + ac);
        {
            const _Float16* gb = Bw + (size_t)br * 512 + k0 + bc;
            *(half8*)&Bs[br * 32 + bc] = *(const half8*)(gb);
            *(half8*)&Bs[br * 32 + bc + 8] = *(const half8*)(gb + 8);
        }
        __syncthreads();
        half8 af[4], bf[4];
#pragma unroll
        for (int m = 0; m < 4; m++) af[m] = *(const half8*)&As[(wr + m * 16 + ln) * 32 + kg * 8];
#pragma unroll
        for (int n = 0; n < 4; n++) bf[n] = *(const half8*)&Bs[(wc + n * 16 + ln) * 32 + kg * 8];
#pragma unroll
        for (int m = 0; m < 4; m++)
#pragma unroll
            for (int n = 0; n < 4; n++)
                acc[m][n] = __builtin_amdgcn_mfma_f32_16x16x32_f16(af[m], bf[n], acc[m][n], 0, 0, 0);
        __syncthreads();
    }
#pragma unroll
    for (int m = 0; m < 4; m++)
#pragma unroll
        for (int n = 0; n < 4; n++) {
            const int col = wc + n * 16 + ln;
            const float bv = biasv[col];
#pragma unroll
            for (int q = 0; q < 4; q++) {
                const int row = m0 + wr + m * 16 + kg * 4 + q;
                out[(size_t)row * 256 + col] = acc[m][n][q] + bv;
            }
        }
}

// ---------------------------------------------------------------------------
extern "C" void kernel_launch(void* const* d_in, const int* in_sizes, int n_in,
                              void* d_out, int out_size, void* d_ws, size_t ws_size,
                              hipStream_t stream) {
    const float* states = (const float*)d_in[0];
    const int*   term   = (const int*)d_in[1];
    const float* h0     = (const float*)d_in[2];
    const float* Wih    = (const float*)d_in[3];
    const float* Whh    = (const float*)d_in[4];
    const float* bih    = (const float*)d_in[5];
    const float* bhh    = (const float*)d_in[6];
    const float* fcw    = (const float*)d_in[7];
    const float* fcb    = (const float*)d_in[8];

    char* ws = (char*)d_ws;
    _Float16* xpw   = (_Float16*)(ws + XPW_OFF);
    _Float16* wih_h = (_Float16*)(ws + WIH_OFF);
    _Float16* fcw_h = (_Float16*)(ws + FCW_OFF);
    float*    bias2 = (float*)(ws + BIAS_OFF);
    _Float16* wres  = (_Float16*)(ws + WRES_OFF);

    conv_w<<<1024, 256, 0, stream>>>(Wih, Whh, fcw, bih, bhh, wih_h, fcw_h, bias2, wres);
    gemm_xproj<<<2048, 256, 0, stream>>>(states, wih_h, bias2, xpw);
    rnn_scan7<<<32, 256, 0, stream>>>(xpw, wres, term, h0, (float*)d_out);
    gemm_logits<<<512, 512, 0, stream>>>((const _Float16*)d_out, fcw_h, fcb, (float*)d_out);
}

// Round 9
// 555.115 us; speedup vs baseline: 2.6695x; 1.7146x over previous
//
#include <hip/hip_runtime.h>
#include <hip/hip_bf16.h>
#include <hip/hip_fp16.h>

// tanh-RNN + FC on MI355X.
// conv_w -> gemm_xproj (f16 MFMA, 128x64 stripe tiles, scan-native xp layout)
// -> rnn_scan8 (32 blocks x 512 thr, 2 waves/SIMD; W_hh EXACTLY resident:
// 384KB in AGPRs (8 waves x 48 frags "+a"-pinned) + 128KB LDS tile; zero
// global loads in the K-loop) -> gemm_logits (in-place over d_out).
// R9 = R8 + fix: wresA per-wave stride 24576 (48 frags x 512), conv bound 196608.

typedef _Float16 half8 __attribute__((ext_vector_type(8)));
typedef _Float16 half4 __attribute__((ext_vector_type(4)));
typedef float f32x4 __attribute__((ext_vector_type(4)));

// ws layout (bytes)
#define XPW_OFF   0UL            // 64MB x_proj f16 (scan-native layout)
#define WIH_OFF   67108864UL     // 512KB f16 W_ih
#define FCW_OFF   67633152UL     // 256KB f16 fc_w
#define BIAS_OFF  67895296UL     // 2KB f32 bias2
#define WRESA_OFF 67897344UL     // 384KB AGPR W frags [w(8)][nt(3)][s(16)][lane(64)][8]
#define WRESL_OFF 68683776UL     // 128KB LDS  W frags [w(8)][s(16)][lane(64)][8]

// column stripe ntg = nt*8 + w (nt=0..2 AGPR) or 24+w (LDS); col = ntg*16 + ln.

// ---------------------------------------------------------------------------
// conv_w: f16 W_ih, fc_w; bias2 = b_ih + b_hh; W_hh -> B-frag layouts.
// B-frag value: lane l, frag (ntg,s), elem i = Whh[ntg*16+(l&15)][s*32+(l>>4)*8+i]
// wresA element index = w*24576 + nt*8192 + s*512 + l*8 + i  (rest = idx>>13 = w*3+nt)
// ---------------------------------------------------------------------------
__global__ void conv_w(const float* __restrict__ Wih, const float* __restrict__ Whh,
                       const float* __restrict__ fcw, const float* __restrict__ bih,
                       const float* __restrict__ bhh,
                       _Float16* __restrict__ wih_h, _Float16* __restrict__ fcw_h,
                       float* __restrict__ bias2,
                       _Float16* __restrict__ wresA, _Float16* __restrict__ wresL) {
    int idx = blockIdx.x * 256 + threadIdx.x;
    if (idx < 262144) wih_h[idx] = (_Float16)Wih[idx];
    if (idx < 196608) {   // wresA: [w(8)][nt(3)][s(16)][lane][8]  (8*3*16*64*8)
        const int i = idx & 7, l = (idx >> 3) & 63, s = (idx >> 9) & 15;
        const int rest = idx >> 13;              // w*3 + nt, 0..23
        const int w = rest / 3, nt = rest % 3;
        const int ntg = nt * 8 + w;
        wresA[idx] = (_Float16)Whh[(size_t)(ntg * 16 + (l & 15)) * 512 + s * 32 + (l >> 4) * 8 + i];
    }
    if (idx < 65536) {    // wresL: [w(8)][s(16)][lane][8], ntg = 24+w
        const int i = idx & 7, l = (idx >> 3) & 63, s = (idx >> 9) & 15, w = idx >> 13;
        const int ntg = 24 + w;
        wresL[idx] = (_Float16)Whh[(size_t)(ntg * 16 + (l & 15)) * 512 + s * 32 + (l >> 4) * 8 + i];
    }
    if (idx < 131072) fcw_h[idx] = (_Float16)fcw[idx];
    if (idx < 512) bias2[idx] = bih[idx] + bhh[idx];
}

// ---------------------------------------------------------------------------
// K1: x_proj = states @ W_ih^T + bias2, scan-native output:
//   dst = (bg*128+t)*8192 + (w_s*64 + kgs*16 + ln)*16 + qs*4 + nt
//   where b = bg*16 + kgs*4 + qs, col = (nt*8 + w_s)*16 + ln.
// Grid 4096 = 512 b x 8 w_s; block computes 128 t x 64 cols (stripes of w_s).
// XCD-grouped: all 8 stripe-blocks of a batch land on one XCD (A L2 reuse).
// ---------------------------------------------------------------------------
__global__ __launch_bounds__(256) void gemm_xproj(const float* __restrict__ A,
                                                  const _Float16* __restrict__ Bw,
                                                  const float* __restrict__ bias2,
                                                  _Float16* __restrict__ out) {
    __shared__ _Float16 As[128 * 32];
    __shared__ _Float16 Bs[64 * 32];
    const int tid = threadIdx.x;
    const int s_ = blockIdx.x;
    const int z = s_ & 7, k_ = s_ >> 3;
    const int gid = z * 512 + k_;
    const int b = gid >> 3;              // batch
    const int wsp = gid & 7;             // stripe group w_s
    const int lane = tid & 63, w1 = tid >> 6;
    const int ln = lane & 15, kg = lane >> 4;

    f32x4 acc[2][4];
#pragma unroll
    for (int m = 0; m < 2; m++)
#pragma unroll
        for (int n = 0; n < 4; n++) acc[m][n] = (f32x4)0.0f;

    const int sr = tid >> 1, sc = (tid & 1) * 16;      // A staging: 128 x 32
    const int sr2 = tid >> 2, sc2 = (tid & 3) * 8;     // B staging: 64 x 32
    const int brow = (sr2 >> 4) * 128 + wsp * 16 + (sr2 & 15);

    for (int k0 = 0; k0 < 512; k0 += 32) {
        {
            const float* ga = A + (size_t)(b * 128 + sr) * 512 + k0 + sc;
            float4 f0 = *(const float4*)(ga + 0);
            float4 f1 = *(const float4*)(ga + 4);
            float4 f2 = *(const float4*)(ga + 8);
            float4 f3 = *(const float4*)(ga + 12);
            half8 h0, h1;
            h0[0] = (_Float16)f0.x; h0[1] = (_Float16)f0.y; h0[2] = (_Float16)f0.z; h0[3] = (_Float16)f0.w;
            h0[4] = (_Float16)f1.x; h0[5] = (_Float16)f1.y; h0[6] = (_Float16)f1.z; h0[7] = (_Float16)f1.w;
            h1[0] = (_Float16)f2.x; h1[1] = (_Float16)f2.y; h1[2] = (_Float16)f2.z; h1[3] = (_Float16)f2.w;
            h1[4] = (_Float16)f3.x; h1[5] = (_Float16)f3.y; h1[6] = (_Float16)f3.z; h1[7] = (_Float16)f3.w;
            *(half8*)&As[sr * 32 + sc] = h0;
            *(half8*)&As[sr * 32 + sc + 8] = h1;
        }
        *(half8*)&Bs[sr2 * 32 + sc2] = *(const half8*)(Bw + (size_t)brow * 512 + k0 + sc2);
        __syncthreads();
        half8 af[2], bf[4];
#pragma unroll
        for (int m = 0; m < 2; m++) af[m] = *(const half8*)&As[(w1 * 32 + m * 16 + ln) * 32 + kg * 8];
#pragma unroll
        for (int n = 0; n < 4; n++) bf[n] = *(const half8*)&Bs[(n * 16 + ln) * 32 + kg * 8];
#pragma unroll
        for (int m = 0; m < 2; m++)
#pragma unroll
            for (int n = 0; n < 4; n++)
                acc[m][n] = __builtin_amdgcn_mfma_f32_16x16x32_f16(af[m], bf[n], acc[m][n], 0, 0, 0);
        __syncthreads();
    }
    // epilogue: 8 half4 stores into scan-native layout
    const int bg = b >> 4, kgs = (b >> 2) & 3, qs = b & 3;
    float bv[4];
#pragma unroll
    for (int n = 0; n < 4; n++) bv[n] = bias2[(n * 8 + wsp) * 16 + ln];
    const size_t tb = (size_t)(bg * 128) * 8192 + (size_t)(wsp * 64 + kgs * 16 + ln) * 16 + qs * 4;
#pragma unroll
    for (int m = 0; m < 2; m++)
#pragma unroll
        for (int q = 0; q < 4; q++) {
            half4 v;
#pragma unroll
            for (int n = 0; n < 4; n++) v[n] = (_Float16)(acc[m][n][q] + bv[n]);
            const int t = w1 * 32 + m * 16 + kg * 4 + q;
            *(half4*)&out[tb + (size_t)t * 8192] = v;
        }
}

// ---------------------------------------------------------------------------
// Scan v8 (fixed): 32 blocks x 512 thr (8 waves, 2/SIMD, 256 regs/wave).
// Wave w owns stripes ntg {w, 8+w, 16+w} as 48 AGPR frags (192 regs) +
// stripe 24+w from a 128KB LDS-resident W tile. h in k8-major LDS.
// No global loads in the K-loop.
// ---------------------------------------------------------------------------
__global__ __launch_bounds__(512, 2) void rnn_scan8(
    const _Float16* __restrict__ xps,     // scan-native x_proj
    const _Float16* __restrict__ wresA,   // AGPR frags
    const _Float16* __restrict__ wresL,   // LDS frags
    const int* __restrict__ term,         // [512][128] int32
    const float* __restrict__ h0,         // [512][512] f32
    float* dout) {
    __shared__ __align__(16) _Float16 hb[8192];      // h, k8-major
    __shared__ __align__(16) _Float16 wl[65536];     // W stripes ntg 24..31 (128KB)
    __shared__ unsigned int term_lds[16][4];
    const int tid = threadIdx.x;
    const int bg = blockIdx.x;
    const int R0 = bg * 16;
    const int lane = tid & 63, w = tid >> 6;
    const int ln = lane & 15, kg = lane >> 4;
    _Float16* rnn = (_Float16*)dout;

    // ---- 48 AGPR frags (192 AGPRs); per-wave stride 48*512 = 24576 ----
    half8 wf[48];
    {
        const _Float16* wp = wresA + (size_t)w * 24576 + lane * 8;
#pragma unroll
        for (int f = 0; f < 48; f++) wf[f] = *(const half8*)(wp + (size_t)f * 512);
    }
#pragma unroll
    for (int f = 0; f < 48; f++) asm volatile("" : "+a"(wf[f]));

    // ---- stage LDS W tile (128KB linear) ----
    for (int u = 0; u < 16; u++) {
        const int o = (u * 512 + tid) * 8;
        *(half8*)&wl[o] = *(const half8*)(wresL + o);
    }
    // ---- h0 -> hb (f32 -> f16, k8-major) ----
    {
        const int r = tid >> 5, c0 = (tid & 31) * 16;
        const float* gh = h0 + (size_t)(R0 + r) * 512 + c0;
        half8 v0, v1;
#pragma unroll
        for (int i = 0; i < 8; i++) { v0[i] = (_Float16)gh[i]; v1[i] = (_Float16)gh[8 + i]; }
        const int kb = c0 >> 3;
        *(half8*)&hb[kb * 128 + r * 8] = v0;
        *(half8*)&hb[(kb + 1) * 128 + r * 8] = v1;
    }
    // ---- termination bitmasks ----
    if (tid < 64) {
        const int r = tid >> 2, word = tid & 3;
        unsigned int m = 0;
        for (int b2 = 0; b2 < 32; b2++)
            m |= (term[(R0 + r) * 128 + word * 32 + b2] ? 1u : 0u) << b2;
        term_lds[r][word] = m;
    }
    __syncthreads();

    const _Float16* xpt = xps + (size_t)(bg * 128) * 8192 + tid * 16;
    const _Float16* bl = &wl[(size_t)w * 8192];
    unsigned int tmask[4];

#pragma unroll 1
    for (int t = 0; t < 128; ++t) {
        if ((t & 31) == 0) {
#pragma unroll
            for (int q = 0; q < 4; q++) tmask[q] = term_lds[kg * 4 + q][t >> 5];
        }
        // xp(t): 32B/thread, layout [q][nt]; lands during the MFMA phase
        const half8 xv0 = *(const half8*)(xpt);
        const half8 xv1 = *(const half8*)(xpt + 8);
        xpt += 8192;

        f32x4 acc[4];
#pragma unroll
        for (int n = 0; n < 4; n++) acc[n] = (f32x4)0.0f;

#pragma unroll
        for (int s = 0; s < 16; s++) {
            const half8 a = *(const half8*)&hb[(s * 4 + kg) * 128 + ln * 8];
            acc[0] = __builtin_amdgcn_mfma_f32_16x16x32_f16(a, wf[s],      acc[0], 0, 0, 0);
            acc[1] = __builtin_amdgcn_mfma_f32_16x16x32_f16(a, wf[16 + s], acc[1], 0, 0, 0);
            acc[2] = __builtin_amdgcn_mfma_f32_16x16x32_f16(a, wf[32 + s], acc[2], 0, 0, 0);
            const half8 b4 = *(const half8*)(bl + s * 512 + lane * 8);
            acc[3] = __builtin_amdgcn_mfma_f32_16x16x32_f16(a, b4, acc[3], 0, 0, 0);
        }
        __syncthreads();   // all hb reads of h(t) done

        // ---- tanh; rnn_out store (unmasked) + masked h(t+1) -> hb ----
#pragma unroll
        for (int q = 0; q < 4; q++)
#pragma unroll
            for (int nt = 0; nt < 4; nt++) {
                const int u = q * 4 + nt;
                const float xval = (float)(u < 8 ? xv0[u] : xv1[u - 8]);
                const float pre = acc[nt][q] + xval;
                const float e = __expf(2.0f * pre);
                const float hn = 1.0f - 2.0f / (e + 1.0f);
                const _Float16 hh = (_Float16)hn;
                const int c = (nt * 8 + w) * 16 + ln;
                rnn[(size_t)((R0 + kg * 4 + q) * 128 + t) * 512 + c] = hh;
                hb[(c >> 3) * 128 + (kg * 4 + q) * 8 + (c & 7)] =
                    ((tmask[q] >> (t & 31)) & 1) ? (_Float16)0.0f : hh;
            }
        __syncthreads();   // h(t+1) visible
    }

    // ---- h_final (masked h(128)) -> f32 at d_out + 65536*256 ----
    {
        const int r = tid >> 5, c0 = (tid & 31) * 16;
        const int kb = c0 >> 3;
        half8 v0 = *(const half8*)&hb[kb * 128 + r * 8];
        half8 v1 = *(const half8*)&hb[(kb + 1) * 128 + r * 8];
        float* gf = dout + (size_t)65536 * 256 + (size_t)(R0 + r) * 512 + c0;
#pragma unroll
        for (int i = 0; i < 8; i++) { gf[i] = (float)v0[i]; gf[8 + i] = (float)v1[i]; }
    }
}

// ---------------------------------------------------------------------------
// K3: logits[65536,256] (f32) = rnn_out(f16, in d_out) @ fc_w^T + fc_b
// ---------------------------------------------------------------------------
__global__ __launch_bounds__(512) void gemm_logits(const _Float16* Arnn,
                                                   const _Float16* __restrict__ Bw,
                                                   const float* __restrict__ biasv,
                                                   float* out) {
    __shared__ _Float16 As[128 * 32];
    __shared__ _Float16 Bs[256 * 32];
    const int tid = threadIdx.x;
    const int m0 = blockIdx.x * 128;
    const int lane = tid & 63, w = tid >> 6;
    const int wr = (w >> 2) * 64, wc = (w & 3) * 64;
    const int ln = lane & 15, kg = lane >> 4;

    f32x4 acc[4][4];
#pragma unroll
    for (int m = 0; m < 4; m++)
#pragma unroll
        for (int n = 0; n < 4; n++) acc[m][n] = (f32x4)0.0f;

    const int ar = tid >> 2, ac = (tid & 3) * 8;
    const int br = tid >> 1, bc = (tid & 1) * 16;

    for (int k0 = 0; k0 < 512; k0 += 32) {
        *(half8*)&As[ar * 32 + ac] = *(const half8*)(Arnn + (size_t)(m0 + ar) * 512 + k0 + ac);
        {
            const _Float16* gb = Bw + (size_t)br * 512 + k0 + bc;
            *(half8*)&Bs[br * 32 + bc] = *(const half8*)(gb);
            *(half8*)&Bs[br * 32 + bc + 8] = *(const half8*)(gb + 8);
        }
        __syncthreads();
        half8 af[4], bf[4];
#pragma unroll
        for (int m = 0; m < 4; m++) af[m] = *(const half8*)&As[(wr + m * 16 + ln) * 32 + kg * 8];
#pragma unroll
        for (int n = 0; n < 4; n++) bf[n] = *(const half8*)&Bs[(wc + n * 16 + ln) * 32 + kg * 8];
#pragma unroll
        for (int m = 0; m < 4; m++)
#pragma unroll
            for (int n = 0; n < 4; n++)
                acc[m][n] = __builtin_amdgcn_mfma_f32_16x16x32_f16(af[m], bf[n], acc[m][n], 0, 0, 0);
        __syncthreads();
    }
#pragma unroll
    for (int m = 0; m < 4; m++)
#pragma unroll
        for (int n = 0; n < 4; n++) {
            const int col = wc + n * 16 + ln;
            const float bv = biasv[col];
#pragma unroll
            for (int q = 0; q < 4; q++) {
                const int row = m0 + wr + m * 16 + kg * 4 + q;
                out[(size_t)row * 256 + col] = acc[m][n][q] + bv;
            }
        }
}

// ---------------------------------------------------------------------------
extern "C" void kernel_launch(void* const* d_in, const int* in_sizes, int n_in,
                              void* d_out, int out_size, void* d_ws, size_t ws_size,
                              hipStream_t stream) {
    const float* states = (const float*)d_in[0];
    const int*   term   = (const int*)d_in[1];
    const float* h0     = (const float*)d_in[2];
    const float* Wih    = (const float*)d_in[3];
    const float* Whh    = (const float*)d_in[4];
    const float* bih    = (const float*)d_in[5];
    const float* bhh    = (const float*)d_in[6];
    const float* fcw    = (const float*)d_in[7];
    const float* fcb    = (const float*)d_in[8];

    char* ws = (char*)d_ws;
    _Float16* xpw   = (_Float16*)(ws + XPW_OFF);
    _Float16* wih_h = (_Float16*)(ws + WIH_OFF);
    _Float16* fcw_h = (_Float16*)(ws + FCW_OFF);
    float*    bias2 = (float*)(ws + BIAS_OFF);
    _Float16* wresA = (_Float16*)(ws + WRESA_OFF);
    _Float16* wresL = (_Float16*)(ws + WRESL_OFF);

    conv_w<<<1024, 256, 0, stream>>>(Wih, Whh, fcw, bih, bhh, wih_h, fcw_h, bias2, wresA, wresL);
    gemm_xproj<<<4096, 256, 0, stream>>>(states, wih_h, bias2, xpw);
    rnn_scan8<<<32, 512, 0, stream>>>(xpw, wresA, wresL, term, h0, (float*)d_out);
    gemm_logits<<<512, 512, 0, stream>>>((const _Float16*)d_out, fcw_h, fcb, (float*)d_out);
}

// Round 11
// 536.279 us; speedup vs baseline: 2.7633x; 1.0351x over previous
//
#include <hip/hip_runtime.h>
#include <hip/hip_bf16.h>
#include <hip/hip_fp16.h>

// tanh-RNN + FC on MI355X.
// conv_w -> gemm_xproj (f16 MFMA, scan-native xp layout) -> rnn_scan10
// (32 blocks x 512 thr, 2 waves/SIMD; W_hh resident: 384KB AGPR (8 waves x 48
// "+a"-pinned B-frags) + 128KB LDS tile; no global loads in K-loop; rnn
// stores deferred past barrier2; rcp-based tanh) -> gemm_logits (in-place).

typedef _Float16 half8 __attribute__((ext_vector_type(8)));
typedef _Float16 half4 __attribute__((ext_vector_type(4)));
typedef float f32x4 __attribute__((ext_vector_type(4)));

// ws layout (bytes)
#define XPW_OFF   0UL            // 64MB x_proj f16 (scan-native layout)
#define WIH_OFF   67108864UL     // 512KB f16 W_ih
#define FCW_OFF   67633152UL     // 256KB f16 fc_w
#define BIAS_OFF  67895296UL     // 2KB f32 bias2
#define WRESA_OFF 67897344UL     // 384KB AGPR W frags [w(8)][nt(3)][s(16)][lane(64)][8]
#define WRESL_OFF 68290560UL     // 128KB LDS  W frags [w(8)][s(16)][lane(64)][8]

// column stripe ntg = nt*8 + w (nt=0..2 AGPR) or 24+w (LDS); col = ntg*16 + ln.

// ---------------------------------------------------------------------------
// conv_w: f16 W_ih, fc_w; bias2 = b_ih + b_hh; W_hh -> B-frag layouts.
// B-frag value: lane l, frag (ntg,s), elem i = Whh[ntg*16+(l&15)][s*32+(l>>4)*8+i]
// wresA element index = w*24576 + nt*8192 + s*512 + l*8 + i  (rest = idx>>13 = w*3+nt)
// ---------------------------------------------------------------------------
__global__ void conv_w(const float* __restrict__ Wih, const float* __restrict__ Whh,
                       const float* __restrict__ fcw, const float* __restrict__ bih,
                       const float* __restrict__ bhh,
                       _Float16* __restrict__ wih_h, _Float16* __restrict__ fcw_h,
                       float* __restrict__ bias2,
                       _Float16* __restrict__ wresA, _Float16* __restrict__ wresL) {
    int idx = blockIdx.x * 256 + threadIdx.x;
    if (idx < 262144) wih_h[idx] = (_Float16)Wih[idx];
    if (idx < 196608) {   // wresA: [w(8)][nt(3)][s(16)][lane][8]  (8*3*16*64*8)
        const int i = idx & 7, l = (idx >> 3) & 63, s = (idx >> 9) & 15;
        const int rest = idx >> 13;              // w*3 + nt, 0..23
        const int w = rest / 3, nt = rest % 3;
        const int ntg = nt * 8 + w;
        wresA[idx] = (_Float16)Whh[(size_t)(ntg * 16 + (l & 15)) * 512 + s * 32 + (l >> 4) * 8 + i];
    }
    if (idx < 65536) {    // wresL: [w(8)][s(16)][lane][8], ntg = 24+w
        const int i = idx & 7, l = (idx >> 3) & 63, s = (idx >> 9) & 15, w = idx >> 13;
        const int ntg = 24 + w;
        wresL[idx] = (_Float16)Whh[(size_t)(ntg * 16 + (l & 15)) * 512 + s * 32 + (l >> 4) * 8 + i];
    }
    if (idx < 131072) fcw_h[idx] = (_Float16)fcw[idx];
    if (idx < 512) bias2[idx] = bih[idx] + bhh[idx];
}

// ---------------------------------------------------------------------------
// K1: x_proj = states @ W_ih^T + bias2, scan-native output:
//   dst = (bg*128+t)*8192 + (w_s*64 + kgs*16 + ln)*16 + qs*4 + nt
//   where b = bg*16 + kgs*4 + qs, col = (nt*8 + w_s)*16 + ln.
// Grid 4096 = 512 b x 8 w_s; block computes 128 t x 64 cols (stripes of w_s).
// ---------------------------------------------------------------------------
__global__ __launch_bounds__(256) void gemm_xproj(const float* __restrict__ A,
                                                  const _Float16* __restrict__ Bw,
                                                  const float* __restrict__ bias2,
                                                  _Float16* __restrict__ out) {
    __shared__ _Float16 As[128 * 32];
    __shared__ _Float16 Bs[64 * 32];
    const int tid = threadIdx.x;
    const int s_ = blockIdx.x;
    const int z = s_ & 7, k_ = s_ >> 3;
    const int gid = z * 512 + k_;
    const int b = gid >> 3;              // batch
    const int wsp = gid & 7;             // stripe group w_s
    const int lane = tid & 63, w1 = tid >> 6;
    const int ln = lane & 15, kg = lane >> 4;

    f32x4 acc[2][4];
#pragma unroll
    for (int m = 0; m < 2; m++)
#pragma unroll
        for (int n = 0; n < 4; n++) acc[m][n] = (f32x4)0.0f;

    const int sr = tid >> 1, sc = (tid & 1) * 16;      // A staging: 128 x 32
    const int sr2 = tid >> 2, sc2 = (tid & 3) * 8;     // B staging: 64 x 32
    const int brow = (sr2 >> 4) * 128 + wsp * 16 + (sr2 & 15);

    for (int k0 = 0; k0 < 512; k0 += 32) {
        {
            const float* ga = A + (size_t)(b * 128 + sr) * 512 + k0 + sc;
            float4 f0 = *(const float4*)(ga + 0);
            float4 f1 = *(const float4*)(ga + 4);
            float4 f2 = *(const float4*)(ga + 8);
            float4 f3 = *(const float4*)(ga + 12);
            half8 h0, h1;
            h0[0] = (_Float16)f0.x; h0[1] = (_Float16)f0.y; h0[2] = (_Float16)f0.z; h0[3] = (_Float16)f0.w;
            h0[4] = (_Float16)f1.x; h0[5] = (_Float16)f1.y; h0[6] = (_Float16)f1.z; h0[7] = (_Float16)f1.w;
            h1[0] = (_Float16)f2.x; h1[1] = (_Float16)f2.y; h1[2] = (_Float16)f2.z; h1[3] = (_Float16)f2.w;
            h1[4] = (_Float16)f3.x; h1[5] = (_Float16)f3.y; h1[6] = (_Float16)f3.z; h1[7] = (_Float16)f3.w;
            *(half8*)&As[sr * 32 + sc] = h0;
            *(half8*)&As[sr * 32 + sc + 8] = h1;
        }
        *(half8*)&Bs[sr2 * 32 + sc2] = *(const half8*)(Bw + (size_t)brow * 512 + k0 + sc2);
        __syncthreads();
        half8 af[2], bf[4];
#pragma unroll
        for (int m = 0; m < 2; m++) af[m] = *(const half8*)&As[(w1 * 32 + m * 16 + ln) * 32 + kg * 8];
#pragma unroll
        for (int n = 0; n < 4; n++) bf[n] = *(const half8*)&Bs[(n * 16 + ln) * 32 + kg * 8];
#pragma unroll
        for (int m = 0; m < 2; m++)
#pragma unroll
            for (int n = 0; n < 4; n++)
                acc[m][n] = __builtin_amdgcn_mfma_f32_16x16x32_f16(af[m], bf[n], acc[m][n], 0, 0, 0);
        __syncthreads();
    }
    // epilogue: 8 half4 stores into scan-native layout
    const int bg = b >> 4, kgs = (b >> 2) & 3, qs = b & 3;
    float bv[4];
#pragma unroll
    for (int n = 0; n < 4; n++) bv[n] = bias2[(n * 8 + wsp) * 16 + ln];
    const size_t tb = (size_t)(bg * 128) * 8192 + (size_t)(wsp * 64 + kgs * 16 + ln) * 16 + qs * 4;
#pragma unroll
    for (int m = 0; m < 2; m++)
#pragma unroll
        for (int q = 0; q < 4; q++) {
            half4 v;
#pragma unroll
            for (int n = 0; n < 4; n++) v[n] = (_Float16)(acc[m][n][q] + bv[n]);
            const int t = w1 * 32 + m * 16 + kg * 4 + q;
            *(half4*)&out[tb + (size_t)t * 8192] = v;
        }
}

// ---------------------------------------------------------------------------
// Scan v10: 32 blocks x 512 thr (8 waves, 2/SIMD, 256 regs/wave).
// Wave w owns stripes ntg {w, 8+w, 16+w} as 48 AGPR frags (192 regs) +
// stripe 24+w from a 128KB LDS-resident W tile. h in k8-major LDS.
// rnn stores deferred past barrier2 (drain overlaps next MFMA phase).
// ---------------------------------------------------------------------------
__global__ __launch_bounds__(512, 2) void rnn_scan10(
    const _Float16* __restrict__ xps,     // scan-native x_proj
    const _Float16* __restrict__ wresA,   // AGPR frags
    const _Float16* __restrict__ wresL,   // LDS frags
    const int* __restrict__ term,         // [512][128] int32
    const float* __restrict__ h0,         // [512][512] f32
    float* dout) {
    __shared__ __align__(16) _Float16 hb[8192];      // h, k8-major
    __shared__ __align__(16) _Float16 wl[65536];     // W stripes ntg 24..31 (128KB)
    __shared__ unsigned int term_lds[16][4];
    const int tid = threadIdx.x;
    const int bg = blockIdx.x;
    const int R0 = bg * 16;
    const int lane = tid & 63, w = tid >> 6;
    const int ln = lane & 15, kg = lane >> 4;
    _Float16* rnn = (_Float16*)dout;

    // ---- 48 AGPR frags (192 AGPRs); per-wave stride 48*512 = 24576 ----
    half8 wf[48];
    {
        const _Float16* wp = wresA + (size_t)w * 24576 + lane * 8;
#pragma unroll
        for (int f = 0; f < 48; f++) wf[f] = *(const half8*)(wp + (size_t)f * 512);
    }
#pragma unroll
    for (int f = 0; f < 48; f++) asm volatile("" : "+a"(wf[f]));

    // ---- stage LDS W tile (128KB linear) ----
    for (int u = 0; u < 16; u++) {
        const int o = (u * 512 + tid) * 8;
        *(half8*)&wl[o] = *(const half8*)(wresL + o);
    }
    // ---- h0 -> hb (f32 -> f16, k8-major) ----
    {
        const int r = tid >> 5, c0 = (tid & 31) * 16;
        const float* gh = h0 + (size_t)(R0 + r) * 512 + c0;
        half8 v0, v1;
#pragma unroll
        for (int i = 0; i < 8; i++) { v0[i] = (_Float16)gh[i]; v1[i] = (_Float16)gh[8 + i]; }
        const int kb = c0 >> 3;
        *(half8*)&hb[kb * 128 + r * 8] = v0;
        *(half8*)&hb[(kb + 1) * 128 + r * 8] = v1;
    }
    // ---- termination bitmasks ----
    if (tid < 64) {
        const int r = tid >> 2, word = tid & 3;
        unsigned int m = 0;
        for (int b2 = 0; b2 < 32; b2++)
            m |= (term[(R0 + r) * 128 + word * 32 + b2] ? 1u : 0u) << b2;
        term_lds[r][word] = m;
    }
    __syncthreads();

    const _Float16* xpt = xps + (size_t)(bg * 128) * 8192 + tid * 16;
    const _Float16* bl = &wl[(size_t)w * 8192];
    unsigned int tmask[4];

#pragma unroll 1
    for (int t = 0; t < 128; ++t) {
        if ((t & 31) == 0) {
#pragma unroll
            for (int q = 0; q < 4; q++) tmask[q] = term_lds[kg * 4 + q][t >> 5];
        }
        // xp(t): 32B/thread, layout [q][nt]; lands during the MFMA phase
        const half8 xv0 = *(const half8*)(xpt);
        const half8 xv1 = *(const half8*)(xpt + 8);
        xpt += 8192;

        f32x4 acc[4];
#pragma unroll
        for (int n = 0; n < 4; n++) acc[n] = (f32x4)0.0f;

#pragma unroll
        for (int s = 0; s < 16; s++) {
            const half8 a = *(const half8*)&hb[(s * 4 + kg) * 128 + ln * 8];
            acc[0] = __builtin_amdgcn_mfma_f32_16x16x32_f16(a, wf[s],      acc[0], 0, 0, 0);
            acc[1] = __builtin_amdgcn_mfma_f32_16x16x32_f16(a, wf[16 + s], acc[1], 0, 0, 0);
            acc[2] = __builtin_amdgcn_mfma_f32_16x16x32_f16(a, wf[32 + s], acc[2], 0, 0, 0);
            const half8 b4 = *(const half8*)(bl + s * 512 + lane * 8);
            acc[3] = __builtin_amdgcn_mfma_f32_16x16x32_f16(a, b4, acc[3], 0, 0, 0);
        }
        __syncthreads();   // barrier1: all hb reads of h(t) done

        // ---- tanh (rcp); masked h(t+1) -> hb; keep unmasked in regs ----
        _Float16 hh[16];
#pragma unroll
        for (int q = 0; q < 4; q++)
#pragma unroll
            for (int nt = 0; nt < 4; nt++) {
                const int u = q * 4 + nt;
                const float xval = (float)(u < 8 ? xv0[u] : xv1[u - 8]);
                const float pre = acc[nt][q] + xval;
                const float e = __expf(2.0f * pre);
                const float hn = 1.0f - 2.0f * __builtin_amdgcn_rcpf(e + 1.0f);
                hh[q * 4 + nt] = (_Float16)hn;
                const int c = (nt * 8 + w) * 16 + ln;
                hb[(c >> 3) * 128 + (kg * 4 + q) * 8 + (c & 7)] =
                    ((tmask[q] >> (t & 31)) & 1) ? (_Float16)0.0f : hh[q * 4 + nt];
            }
        __syncthreads();   // barrier2: h(t+1) visible

        // ---- rnn_out stores AFTER barrier2: drain overlaps next MFMA phase ----
#pragma unroll
        for (int q = 0; q < 4; q++)
#pragma unroll
            for (int nt = 0; nt < 4; nt++) {
                const int c = (nt * 8 + w) * 16 + ln;
                rnn[(size_t)((R0 + kg * 4 + q) * 128 + t) * 512 + c] = hh[q * 4 + nt];
            }
    }

    // ---- h_final (masked h(128)) -> f32 at d_out + 65536*256 ----
    {
        const int r = tid >> 5, c0 = (tid & 31) * 16;
        const int kb = c0 >> 3;
        half8 v0 = *(const half8*)&hb[kb * 128 + r * 8];
        half8 v1 = *(const half8*)&hb[(kb + 1) * 128 + r * 8];
        float* gf = dout + (size_t)65536 * 256 + (size_t)(R0 + r) * 512 + c0;
#pragma unroll
        for (int i = 0; i < 8; i++) { gf[i] = (float)v0[i]; gf[8 + i] = (float)v1[i]; }
    }
}

// ---------------------------------------------------------------------------
// K3: logits[65536,256] (f32) = rnn_out(f16, in d_out) @ fc_w^T + fc_b
// ---------------------------------------------------------------------------
__global__ __launch_bounds__(512) void gemm_logits(const _Float16* Arnn,
                                                   const _Float16* __restrict__ Bw,
                                                   const float* __restrict__ biasv,
                                                   float* out) {
    __shared__ _Float16 As[128 * 32];
    __shared__ _Float16 Bs[256 * 32];
    const int tid = threadIdx.x;
    const int m0 = blockIdx.x * 128;
    const int lane = tid & 63, w = tid >> 6;
    const int wr = (w >> 2) * 64, wc = (w & 3) * 64;
    const int ln = lane & 15, kg = lane >> 4;

    f32x4 acc[4][4];
#pragma unroll
    for (int m = 0; m < 4; m++)
#pragma unroll
        for (int n = 0; n < 4; n++) acc[m][n] = (f32x4)0.0f;

    const int ar = tid >> 2, ac = (tid & 3) * 8;
    const int br = tid >> 1, bc = (tid & 1) * 16;

    for (int k0 = 0; k0 < 512; k0 += 32) {
        *(half8*)&As[ar * 32 + ac] = *(const half8*)(Arnn + (size_t)(m0 + ar) * 512 + k0 + ac);
        {
            const _Float16* gb = Bw + (size_t)br * 512 + k0 + bc;
            *(half8*)&Bs[br * 32 + bc] = *(const half8*)(gb);
            *(half8*)&Bs[br * 32 + bc + 8] = *(const half8*)(gb + 8);
        }
        __syncthreads();
        half8 af[4], bf[4];
#pragma unroll
        for (int m = 0; m < 4; m++) af[m] = *(const half8*)&As[(wr + m * 16 + ln) * 32 + kg * 8];
#pragma unroll
        for (int n = 0; n < 4; n++) bf[n] = *(const half8*)&Bs[(wc + n * 16 + ln) * 32 + kg * 8];
#pragma unroll
        for (int m = 0; m < 4; m++)
#pragma unroll
            for (int n = 0; n < 4; n++)
                acc[m][n] = __builtin_amdgcn_mfma_f32_16x16x32_f16(af[m], bf[n], acc[m][n], 0, 0, 0);
        __syncthreads();
    }
#pragma unroll
    for (int m = 0; m < 4; m++)
#pragma unroll
        for (int n = 0; n < 4; n++) {
            const int col = wc + n * 16 + ln;
            const float bv = biasv[col];
#pragma unroll
            for (int q = 0; q < 4; q++) {
                const int row = m0 + wr + m * 16 + kg * 4 + q;
                out[(size_t)row * 256 + col] = acc[m][n][q] + bv;
            }
        }
}

// ---------------------------------------------------------------------------
extern "C" void kernel_launch(void* const* d_in, const int* in_sizes, int n_in,
                              void* d_out, int out_size, void* d_ws, size_t ws_size,
                              hipStream_t stream) {
    const float* states = (const float*)d_in[0];
    const int*   term   = (const int*)d_in[1];
    const float* h0     = (const float*)d_in[2];
    const float* Wih    = (const float*)d_in[3];
    const float* Whh    = (const float*)d_in[4];
    const float* bih    = (const float*)d_in[5];
    const float* bhh    = (const float*)d_in[6];
    const float* fcw    = (const float*)d_in[7];
    const float* fcb    = (const float*)d_in[8];

    char* ws = (char*)d_ws;
    _Float16* xpw   = (_Float16*)(ws + XPW_OFF);
    _Float16* wih_h = (_Float16*)(ws + WIH_OFF);
    _Float16* fcw_h = (_Float16*)(ws + FCW_OFF);
    float*    bias2 = (float*)(ws + BIAS_OFF);
    _Float16* wresA = (_Float16*)(ws + WRESA_OFF);
    _Float16* wresL = (_Float16*)(ws + WRESL_OFF);

    conv_w<<<1024, 256, 0, stream>>>(Wih, Whh, fcw, bih, bhh, wih_h, fcw_h, bias2, wresA, wresL);
    gemm_xproj<<<4096, 256, 0, stream>>>(states, wih_h, bias2, xpw);
    rnn_scan10<<<32, 512, 0, stream>>>(xpw, wresA, wresL, term, h0, (float*)d_out);
    gemm_logits<<<512, 512, 0, stream>>>((const _Float16*)d_out, fcw_h, fcb, (float*)d_out);
}